// Round 1
// baseline (471.654 us; speedup 1.0000x reference)
//
#include <hip/hip_runtime.h>

typedef float f4 __attribute__((ext_vector_type(4)));

#define IN_H 128
#define IN_W 128
#define NCH  128
#define NB   8
#define UPN  256

constexpr int CH  = 16;   // channels per block chunk
constexpr int SEG = 16;   // output rows per block
constexpr int XR_STRIDE = 20;  // floats per col in input ring (16 + 4 pad)
constexpr int U_STRIDE  = 24;  // floats per col in u row (16 + 8 pad)

__device__ __forceinline__ float cubic_k(float x) {
  // Keys cubic, a = -0.5, x >= 0
  float r = 0.f;
  if (x < 1.f)      r = (1.5f * x - 2.5f) * x * x + 1.f;
  else if (x < 2.f) r = ((-0.5f * x + 2.5f) * x - 4.f) * x + 2.f;
  return r;
}

__device__ __forceinline__ int base_u(int r) { return (r >> 1) - 2 + (r & 1); }

__device__ __forceinline__ f4 leaky4(f4 v) {
  f4 r;
  r.x = v.x > 0.f ? v.x : 0.01f * v.x;
  r.y = v.y > 0.f ? v.y : 0.01f * v.y;
  r.z = v.z > 0.f ? v.z : 0.01f * v.z;
  r.w = v.w > 0.f ? v.w : 0.01f * v.w;
  return r;
}

__global__ __launch_bounds__(256, 2)
void actfilter_kernel(const float* __restrict__ x, float* __restrict__ out) {
  __shared__ __align__(16) float xr[4][IN_W][XR_STRIDE];  // 40960 B
  __shared__ __align__(16) float u[IN_W][U_STRIDE];       // 12288 B
  __shared__ __align__(16) float upw[UPN][4];             //  4096 B
  __shared__ __align__(16) float dww[IN_H][8];            //  4096 B

  const int tid = threadIdx.x;

  // XCD-friendly swizzle: 8 channel-chunks of the same (b,seg) stay on one XCD.
  int bid  = blockIdx.x;
  int work = (bid & 7) * 64 + (bid >> 3);
  const int q   = work & 7;          // channel chunk
  const int bs  = work >> 3;
  const int b   = bs >> 3;
  const int seg = bs & 7;
  const int c0  = q * CH;
  const int i0  = seg * SEG;

  // ---- build weight tables (once per block) ----
  {
    int o = tid;                     // 0..255 upsample rows
    int k = o >> 1;
    int base = (o & 1) ? (k - 1) : (k - 2);
    float s = 0.5f * o - 0.25f;
    float w[4]; float sum = 0.f;
#pragma unroll
    for (int t = 0; t < 4; ++t) {
      int tap = base + t;
      float wt = (tap >= 0 && tap < IN_H) ? cubic_k(fabsf(s - (float)tap)) : 0.f;
      w[t] = wt; sum += wt;
    }
    float inv = 1.f / sum;
#pragma unroll
    for (int t = 0; t < 4; ++t) upw[o][t] = w[t] * inv;
  }
  if (tid < IN_H) {
    int j = tid;                     // 0..127 downsample rows
    float s = 2.f * j + 0.5f;
    float w[8]; float sum = 0.f;
#pragma unroll
    for (int t = 0; t < 8; ++t) {
      int tap = 2 * j - 3 + t;
      float wt = (tap >= 0 && tap < UPN) ? cubic_k(0.5f * fabsf(s - (float)tap)) : 0.f;
      w[t] = wt; sum += wt;
    }
    float inv = 1.f / sum;
#pragma unroll
    for (int t = 0; t < 8; ++t) dww[j][t] = w[t] * inv;
  }
  __syncthreads();

  // ---- per-thread hoisted weights ----
  const int g  = tid & 3;            // channel quad (4 floats)
  const int cp = tid >> 2;           // col pair 0..63
  const int j0 = cp * 2;

  float wv[10][4];
#pragma unroll
  for (int m = 0; m < 10; ++m) {
    int cu = 2 * j0 - 3 + m;
    cu = min(max(cu, 0), UPN - 1);
#pragma unroll
    for (int t = 0; t < 4; ++t) wv[m][t] = upw[cu][t];
  }
  float dw0[8], dw1[8];
#pragma unroll
  for (int t = 0; t < 8; ++t) { dw0[t] = dww[j0][t]; dw1[t] = dww[j0 + 1][t]; }

  f4 accA[4], accB[4];
#pragma unroll
  for (int s2 = 0; s2 < 4; ++s2) { accA[s2] = (f4){0.f,0.f,0.f,0.f}; accB[s2] = (f4){0.f,0.f,0.f,0.f}; }

  const int r_lo = max(2 * i0 - 3, 0);
  const int r_hi = min(2 * i0 + 2 * SEG + 2, UPN - 1);

  const float* xbase = x   + (size_t)b * IN_H * IN_W * NCH;
  float*       obase = out + (size_t)b * IN_H * IN_W * NCH;

  // ---- preload 4 ring rows ----
  const int base0 = base_u(r_lo);
#pragma unroll
  for (int n0 = 0; n0 < 4; ++n0) {
    int n  = base0 + n0;
    int cr = min(max(n, 0), IN_H - 1);
    const float* src = xbase + (size_t)cr * IN_W * NCH + c0;
    int slot = n & 3;
#pragma unroll
    for (int pi = 0; pi < 2; ++pi) {
      int p = tid + pi * 256;
      int col = p >> 2, gg = p & 3;
      f4 val = *(const f4*)(src + col * NCH + gg * 4);
      *(f4*)&xr[slot][col][gg * 4] = val;
    }
  }
  int loaded = base0 + 3;
  int pend_row = -1000;
  f4 pend0, pend1;

  for (int r = r_lo; r <= r_hi; ++r) {
    // ---- write pending staged row (loads were issued last iteration) ----
    if (pend_row > loaded) {
      int slot = pend_row & 3;
      {
        int p = tid;        int col = p >> 2, gg = p & 3;
        *(f4*)&xr[slot][col][gg * 4] = pend0;
      }
      {
        int p = tid + 256;  int col = p >> 2, gg = p & 3;
        *(f4*)&xr[slot][col][gg * 4] = pend1;
      }
      loaded = pend_row;
      pend_row = -1000;
    }
    __syncthreads();

    // ---- H-upsample into u ----
    const int rb = base_u(r);
    {
      float w0 = upw[r][0], w1 = upw[r][1], w2 = upw[r][2], w3 = upw[r][3];
      int s0 = rb & 3, s1 = (rb + 1) & 3, s2 = (rb + 2) & 3, s3 = (rb + 3) & 3;
#pragma unroll
      for (int pi = 0; pi < 2; ++pi) {
        int p = tid + pi * 256;
        int col = p >> 2, gg = p & 3;
        f4 a0 = *(const f4*)&xr[s0][col][gg * 4];
        f4 a1 = *(const f4*)&xr[s1][col][gg * 4];
        f4 a2 = *(const f4*)&xr[s2][col][gg * 4];
        f4 a3 = *(const f4*)&xr[s3][col][gg * 4];
        f4 uv = w0 * a0 + w1 * a1 + w2 * a2 + w3 * a3;
        *(f4*)&u[col][gg * 4] = uv;
      }
    }
    __syncthreads();

    // ---- issue next row's global loads early (latency hides under W-pipeline) ----
    if (r < r_hi) {
      int nb2 = base_u(r + 1) + 3;
      if (nb2 > loaded) {
        int cr = min(max(nb2, 0), IN_H - 1);
        const float* src = xbase + (size_t)cr * IN_W * NCH + c0;
        {
          int p = tid;        int col = p >> 2, gg = p & 3;
          pend0 = *(const f4*)(src + col * NCH + gg * 4);
        }
        {
          int p = tid + 256;  int col = p >> 2, gg = p & 3;
          pend1 = *(const f4*)(src + col * NCH + gg * 4);
        }
        pend_row = nb2;
      }
    }

    // ---- W pipeline in registers ----
    f4 uu[8];
#pragma unroll
    for (int k = 0; k < 8; ++k) {
      int ucol = min(max(j0 - 3 + k, 0), IN_W - 1);
      uu[k] = *(const f4*)&u[ucol][g * 4];
    }
    f4 lv[10];
#pragma unroll
    for (int m = 0; m < 10; ++m) {
      f4 v = wv[m][0] * uu[(m >> 1) + 0] + wv[m][1] * uu[(m >> 1) + 1]
           + wv[m][2] * uu[(m >> 1) + 2] + wv[m][3] * uu[(m >> 1) + 3];
      lv[m] = leaky4(v);
    }
    f4 z0 = (f4){0.f,0.f,0.f,0.f}, z1 = (f4){0.f,0.f,0.f,0.f};
#pragma unroll
    for (int t = 0; t < 8; ++t) {
      z0 += dw0[t] * lv[t];
      z1 += dw1[t] * lv[2 + t];
    }

    // ---- down-H accumulate into pending output rows ----
    const int ilo = max(i0, (r - 3) >> 1);
    const int ihi = min(i0 + SEG - 1, (r + 3) >> 1);
#pragma unroll
    for (int s = 0; s < 4; ++s) {          // static accumulator slot
      int i = ilo + ((s - ilo) & 3);
      if (i <= ihi) {
        float w = dww[i][r - 2 * i + 3];
        accA[s] += w * z0;
        accB[s] += w * z1;
        bool done = (r == 2 * i + 4) || (r == UPN - 1 && 2 * i + 4 > UPN - 1);
        if (done) {
          float* dst = obase + ((size_t)i * IN_W + j0) * NCH + c0 + g * 4;
          *(f4*)dst         = accA[s];
          *(f4*)(dst + NCH) = accB[s];
          accA[s] = (f4){0.f,0.f,0.f,0.f};
          accB[s] = (f4){0.f,0.f,0.f,0.f};
        }
      }
    }
  }
}

extern "C" void kernel_launch(void* const* d_in, const int* in_sizes, int n_in,
                              void* d_out, int out_size, void* d_ws, size_t ws_size,
                              hipStream_t stream) {
  const float* x = (const float*)d_in[0];
  float* out = (float*)d_out;
  actfilter_kernel<<<dim3(512), dim3(256), 0, stream>>>(x, out);
}

// Round 2
// 360.068 us; speedup vs baseline: 1.3099x; 1.3099x over previous
//
#include <hip/hip_runtime.h>

typedef float f4 __attribute__((ext_vector_type(4)));

#define IN_H 128
#define IN_W 128
#define NCH  128
#define UPN  256

constexpr int SEG  = 16;            // output rows per block
constexpr int COLS = 16;            // output cols per block
constexpr int ICW  = 22;            // input-col window (cols jc0-3 .. jc0+18)
constexpr int NTASK = ICW * 32;     // 704 f4-tasks per row (22 cols x 32 ch-quads)

__device__ __forceinline__ float cubic_k(float x) {
  // Keys cubic, a = -0.5, x >= 0
  float r = 0.f;
  if (x < 1.f)      r = (1.5f * x - 2.5f) * x * x + 1.f;
  else if (x < 2.f) r = ((-0.5f * x + 2.5f) * x - 4.f) * x + 2.f;
  return r;
}

__device__ __forceinline__ int base_u(int r) { return (r >> 1) - 2 + (r & 1); }

__device__ __forceinline__ f4 leaky4(f4 v) {
  f4 r;
  r.x = v.x > 0.f ? v.x : 0.01f * v.x;
  r.y = v.y > 0.f ? v.y : 0.01f * v.y;
  r.z = v.z > 0.f ? v.z : 0.01f * v.z;
  r.w = v.w > 0.f ? v.w : 0.01f * v.w;
  return r;
}

// global -> LDS direct copy, 16 B per lane. LDS dest is wave-uniform base
// (+ lane*16 added by HW); global source is per-lane.
#define GLDS(g, l)                                                         \
  __builtin_amdgcn_global_load_lds(                                        \
      (const __attribute__((address_space(1))) void*)(g),                  \
      (__attribute__((address_space(3))) void*)(l), 16, 0, 0)

__global__ __launch_bounds__(256, 2)
void actfilter_kernel(const float* __restrict__ x, float* __restrict__ out) {
  // ring of 4 input rows, [col][ch] with full 128-ch runs (contiguous, linear
  // in task order so global_load_lds' lane-linear dest matches exactly)
  __shared__ __align__(16) float xr[4][ICW][NCH];   // 45056 B
  __shared__ __align__(16) float u[ICW][NCH];       // 11264 B  (H-upsampled row)
  __shared__ __align__(16) float upw[UPN][4];       //  4096 B
  __shared__ __align__(16) float dww[IN_H][8];      //  4096 B

  const int tid = threadIdx.x;

  // XCD swizzle: all 64 tiles of one batch image land on one XCD -> halo and
  // L2 line sharing stays within that XCD's private L2.
  int bid  = blockIdx.x;
  int work = (bid & 7) * 64 + (bid >> 3);
  const int cs = work & 7;           // col segment
  const int rs = (work >> 3) & 7;    // row segment
  const int b  = work >> 6;          // batch (== bid & 7)
  const int jc0 = cs * COLS;
  const int i0  = rs * SEG;

  // ---- weight tables (match jax.image.resize bicubic, antialias) ----
  {
    int o = tid;                     // 0..255 upsample positions
    int k = o >> 1;
    int base = (o & 1) ? (k - 1) : (k - 2);
    float s = 0.5f * o - 0.25f;
    float w[4]; float sum = 0.f;
#pragma unroll
    for (int t = 0; t < 4; ++t) {
      int tap = base + t;
      float wt = (tap >= 0 && tap < IN_H) ? cubic_k(fabsf(s - (float)tap)) : 0.f;
      w[t] = wt; sum += wt;
    }
    float inv = 1.f / sum;
#pragma unroll
    for (int t = 0; t < 4; ++t) upw[o][t] = w[t] * inv;
  }
  if (tid < IN_H) {
    int j = tid;                     // 0..127 downsample positions
    float s = 2.f * j + 0.5f;
    float w[8]; float sum = 0.f;
#pragma unroll
    for (int t = 0; t < 8; ++t) {
      int tap = 2 * j - 3 + t;
      float wt = (tap >= 0 && tap < UPN) ? cubic_k(0.5f * fabsf(s - (float)tap)) : 0.f;
      w[t] = wt; sum += wt;
    }
    float inv = 1.f / sum;
#pragma unroll
    for (int t = 0; t < 8; ++t) dww[j][t] = w[t] * inv;
  }
  __syncthreads();

  // ---- per-thread mapping: ch-quad g (0..31), out-col pair cp (0..7) ----
  const int g  = tid & 31;
  const int cp = tid >> 5;
  const int j0 = jc0 + 2 * cp;       // global out col (and j0+1)

  float wv[10][4];
#pragma unroll
  for (int m = 0; m < 10; ++m) {
    int cu = 2 * j0 - 3 + m;
    cu = min(max(cu, 0), UPN - 1);
#pragma unroll
    for (int t = 0; t < 4; ++t) wv[m][t] = upw[cu][t];
  }
  float dw0[8], dw1[8];
#pragma unroll
  for (int t = 0; t < 8; ++t) { dw0[t] = dww[j0][t]; dw1[t] = dww[j0 + 1][t]; }

  f4 accA[4], accB[4];
#pragma unroll
  for (int s2 = 0; s2 < 4; ++s2) {
    accA[s2] = (f4){0.f, 0.f, 0.f, 0.f};
    accB[s2] = (f4){0.f, 0.f, 0.f, 0.f};
  }

  const int r_lo = max(2 * i0 - 3, 0);
  const int r_hi = min(2 * i0 + 2 * SEG + 2, UPN - 1);

  const float* xbase = x   + (size_t)b * IN_H * IN_W * NCH;
  float*       obase = out + (size_t)b * IN_H * IN_W * NCH;

  const int wv64 = tid >> 6;         // wave id (uniform per wave)
  const int lcol = tid >> 5;         // task col piece for staging passes
  const int lq   = tid & 31;

  // stage input row n into ring slot n&3 (3 global_load_lds per thread)
  auto stage = [&](int n) {
    int slot = n & 3;
    int cr = min(max(n, 0), IN_H - 1);
    const float* src = xbase + (size_t)cr * IN_W * NCH;
    char* sbase = (char*)&xr[0][0][0] + slot * (ICW * NCH * 4);
#pragma unroll
    for (int pass = 0; pass < 3; ++pass) {
      int t = tid + pass * 256;
      if (t < NTASK) {
        int col  = t >> 5;
        int gcol = min(max(jc0 - 3 + col, 0), IN_W - 1);
        const float* gp = src + (size_t)gcol * NCH + lq * 4;
        char* lp = sbase + pass * 4096 + wv64 * 1024;  // + lane*16 by HW
        GLDS(gp, lp);
      }
    }
  };

  // ---- preload 4 ring rows ----
  const int base0 = base_u(r_lo);
#pragma unroll
  for (int n0 = 0; n0 < 4; ++n0) stage(base0 + n0);
  int loaded = base0 + 3;
  __syncthreads();                   // drains vmcnt -> ring valid

  for (int r = r_lo; r <= r_hi; ++r) {
    // ---- H-upsample (row direction) into u ----
    const int rb = base_u(r);
    {
      float w0 = upw[r][0], w1 = upw[r][1], w2 = upw[r][2], w3 = upw[r][3];
      const float* x0 = &xr[(rb + 0) & 3][0][0];
      const float* x1 = &xr[(rb + 1) & 3][0][0];
      const float* x2 = &xr[(rb + 2) & 3][0][0];
      const float* x3 = &xr[(rb + 3) & 3][0][0];
      float* uf = &u[0][0];
#pragma unroll
      for (int pass = 0; pass < 3; ++pass) {
        int t = tid + pass * 256;
        if (t < NTASK) {
          int off = t * 4;
          f4 a0 = *(const f4*)(x0 + off);
          f4 a1 = *(const f4*)(x1 + off);
          f4 a2 = *(const f4*)(x2 + off);
          f4 a3 = *(const f4*)(x3 + off);
          *(f4*)(uf + off) = w0 * a0 + w1 * a1 + w2 * a2 + w3 * a3;
        }
      }
    }
    __syncthreads();                 // u ready; all ring reads done

    // ---- issue next row's loads (lands by next barrier; overlaps W work) ----
    if (r < r_hi) {
      int n = base_u(r + 1) + 3;
      if (n > loaded) { stage(n); loaded = n; }
    }

    // ---- W pipeline in registers: col-upsample -> leaky -> col-downsample ----
    f4 uu[8];
#pragma unroll
    for (int k = 0; k < 8; ++k) {
      // local in-col index: (j0-3+k) - (jc0-3) = 2*cp + k  (0..21)
      uu[k] = *(const f4*)&u[2 * cp + k][g * 4];
    }
    f4 lv[10];
#pragma unroll
    for (int m = 0; m < 10; ++m) {
      f4 v = wv[m][0] * uu[(m >> 1) + 0] + wv[m][1] * uu[(m >> 1) + 1]
           + wv[m][2] * uu[(m >> 1) + 2] + wv[m][3] * uu[(m >> 1) + 3];
      lv[m] = leaky4(v);
    }
    f4 z0 = (f4){0.f, 0.f, 0.f, 0.f}, z1 = (f4){0.f, 0.f, 0.f, 0.f};
#pragma unroll
    for (int t = 0; t < 8; ++t) {
      z0 += dw0[t] * lv[t];
      z1 += dw1[t] * lv[2 + t];
    }

    // ---- H-downsample accumulate; write finished output rows ----
    const int ilo = max(i0, (r - 3) >> 1);
    const int ihi = min(i0 + SEG - 1, (r + 3) >> 1);
#pragma unroll
    for (int s = 0; s < 4; ++s) {    // static accumulator slot (no scratch)
      int i = ilo + ((s - ilo) & 3);
      if (i <= ihi) {
        float w = dww[i][r - 2 * i + 3];
        accA[s] += w * z0;
        accB[s] += w * z1;
        bool done = (r == 2 * i + 4) || (r == UPN - 1 && 2 * i + 4 > UPN - 1);
        if (done) {
          float* dst = obase + ((size_t)i * IN_W + j0) * NCH + g * 4;
          *(f4*)dst         = accA[s];   // col j0   : full 512 B run per col
          *(f4*)(dst + NCH) = accB[s];   // col j0+1
          accA[s] = (f4){0.f, 0.f, 0.f, 0.f};
          accB[s] = (f4){0.f, 0.f, 0.f, 0.f};
        }
      }
    }
    __syncthreads();                 // drains vmcnt -> staged row in ring
  }
}

extern "C" void kernel_launch(void* const* d_in, const int* in_sizes, int n_in,
                              void* d_out, int out_size, void* d_ws, size_t ws_size,
                              hipStream_t stream) {
  const float* x = (const float*)d_in[0];
  float* out = (float*)d_out;
  actfilter_kernel<<<dim3(512), dim3(256), 0, stream>>>(x, out);
}

// Round 3
// 75.605 us; speedup vs baseline: 6.2384x; 4.7625x over previous
//
#include <hip/hip_runtime.h>

typedef float f2 __attribute__((ext_vector_type(2)));
typedef float f4 __attribute__((ext_vector_type(4)));

#define IN_H 128
#define IN_W 128
#define NCH  128
#define UPN  256

constexpr int SEG  = 8;    // output rows per block
constexpr int COLS = 32;   // output cols per block
constexpr int CH   = 32;   // channels per block
constexpr int IRW  = 14;   // input row window  (i0-3 .. i0+10)
constexpr int ICW  = 38;   // input col window  (jc0-3 .. jc0+34)
constexpr int NT4  = IRW * ICW * CH / 4;   // 4256 16-byte staging tasks

__device__ __forceinline__ float cubic_k(float x) {
  // Keys cubic, a = -0.5, x >= 0
  float r = 0.f;
  if (x < 1.f)      r = (1.5f * x - 2.5f) * x * x + 1.f;
  else if (x < 2.f) r = ((-0.5f * x + 2.5f) * x - 4.f) * x + 2.f;
  return r;
}

// global -> LDS direct copy, 16 B per lane (LDS dest wave-uniform base).
#define GLDS(g, l)                                                         \
  __builtin_amdgcn_global_load_lds(                                        \
      (const __attribute__((address_space(1))) void*)(g),                  \
      (__attribute__((address_space(3))) void*)(l), 16, 0, 0)

__global__ __launch_bounds__(256, 2)
void actfilter_kernel(const float* __restrict__ x, float* __restrict__ out) {
  __shared__ __align__(16) float xin[IRW][ICW][CH];  // 68096 B
  __shared__ __align__(16) float upw[UPN][4];        //  4096 B
  __shared__ __align__(16) float dww[IN_H][8];       //  4096 B

  const int tid = threadIdx.x;

  // XCD swizzle: batch image -> XCD; within an image, the 4 ch-chunks of a
  // tile and neighboring tiles are dispatch-adjacent (L2 line + halo reuse).
  int bid  = blockIdx.x;
  int work = ((bid & 7) << 8) | (bid >> 3);
  const int b   = work >> 8;
  const int rs  = (work >> 4) & 15;
  const int cs  = (work >> 2) & 3;
  const int chs = work & 3;
  const int i0  = rs * SEG;
  const int jc0 = cs * COLS;
  const int c0  = chs * CH;
  const int mlo = i0 - 3;
  const int mhi = i0 + 10;

  const float* xbase = x   + (size_t)b * IN_H * IN_W * NCH;
  float*       obase = out + (size_t)b * IN_H * IN_W * NCH;

  // ---- issue ALL staging loads first (latency hides under table build) ----
  {
    char* lbase = (char*)&xin[0][0][0] + ((tid >> 6) << 10);
#pragma unroll
    for (int pass = 0; pass < 17; ++pass) {
      int t = tid + pass * 256;
      if (t < NT4) {
        int row   = t / 304;            // 304 = ICW*CH/4 tasks per input row
        int rem   = t - row * 304;
        int col   = rem >> 3;
        int piece = rem & 7;
        int gr = min(max(mlo + row, 0), IN_H - 1);
        int gc = min(max(jc0 - 3 + col, 0), IN_W - 1);
        const float* gp = xbase + ((size_t)gr * IN_W + gc) * NCH + c0 + piece * 4;
        GLDS(gp, lbase + pass * 4096);
      }
    }
  }

  // ---- weight tables (VALU work overlapping the loads) ----
  {
    int o = tid;                       // 0..255 upsample positions
    int k = o >> 1;
    int base = (o & 1) ? (k - 1) : (k - 2);
    float s = 0.5f * o - 0.25f;
    float w[4]; float sum = 0.f;
#pragma unroll
    for (int t = 0; t < 4; ++t) {
      int tap = base + t;
      float wt = (tap >= 0 && tap < IN_H) ? cubic_k(fabsf(s - (float)tap)) : 0.f;
      w[t] = wt; sum += wt;
    }
    float inv = 1.f / sum;
#pragma unroll
    for (int t = 0; t < 4; ++t) upw[o][t] = w[t] * inv;
  }
  if (tid < IN_H) {
    int j = tid;                       // 0..127 downsample positions
    float s = 2.f * j + 0.5f;
    float w[8]; float sum = 0.f;
#pragma unroll
    for (int t = 0; t < 8; ++t) {
      int tap = 2 * j - 3 + t;
      float wt = (tap >= 0 && tap < UPN) ? cubic_k(0.5f * fabsf(s - (float)tap)) : 0.f;
      w[t] = wt; sum += wt;
    }
    float inv = 1.f / sum;
#pragma unroll
    for (int t = 0; t < 8; ++t) dww[j][t] = w[t] * inv;
  }

  __syncthreads();   // the ONLY barrier: xin + tables ready

  // ---- per-thread mapping: col-pair cp (0..15), ch-pair e (0..15) ----
  const int cp = tid >> 4;
  const int e  = tid & 15;
  const int j0 = jc0 + 2 * cp;         // output cols j0, j0+1

  // W-upsample weights for this thread's 10 u-cols (edge renorm baked in)
  f4 wvv[10];
#pragma unroll
  for (int c = 0; c < 10; ++c) {
    int cu = min(max(2 * j0 - 3 + c, 0), UPN - 1);
    wvv[c] = *(const f4*)&upw[cu][0];
  }
  // W-downsample weights for cols j0, j0+1
  float dw0[8], dw1[8];
  {
    f4 a = *(const f4*)&dww[j0][0],     bq = *(const f4*)&dww[j0][4];
    f4 c2 = *(const f4*)&dww[j0 + 1][0], d = *(const f4*)&dww[j0 + 1][4];
#pragma unroll
    for (int t = 0; t < 4; ++t) {
      dw0[t] = a[t]; dw0[t + 4] = bq[t];
      dw1[t] = c2[t]; dw1[t + 4] = d[t];
    }
  }

  const int r_lo = max(2 * i0 - 3, 0);
  const int r_hi = min(2 * i0 + 2 * SEG + 2, UPN - 1);

  f2 tw[4][10];                        // W-upsampled row ring (static-indexed)
  f2 accA[4], accB[4];
#pragma unroll
  for (int s2 = 0; s2 < 4; ++s2) {
    accA[s2] = (f2){0.f, 0.f};
    accB[s2] = (f2){0.f, 0.f};
  }

#define DO_R(RV, S0, S1, S2, S3)                                             \
  do {                                                                       \
    int r = (RV);                                                            \
    if (r >= r_lo && r <= r_hi) {                                            \
      f4 wh = *(const f4*)&upw[r][0];                                        \
      f2 z0 = (f2){0.f, 0.f}, z1 = (f2){0.f, 0.f};                           \
      _Pragma("unroll")                                                      \
      for (int c = 0; c < 10; ++c) {                                         \
        f2 hu = wh.x * tw[S0][c] + wh.y * tw[S1][c]                          \
              + wh.z * tw[S2][c] + wh.w * tw[S3][c];                         \
        f2 lv;                                                               \
        lv.x = fmaxf(hu.x, 0.01f * hu.x);                                    \
        lv.y = fmaxf(hu.y, 0.01f * hu.y);                                    \
        if (c < 8)  z0 += dw0[c] * lv;                                       \
        if (c >= 2) z1 += dw1[c - 2] * lv;                                   \
      }                                                                      \
      int ilo = max(i0, (r - 3) >> 1);                                       \
      int ihi = min(i0 + SEG - 1, (r + 3) >> 1);                             \
      _Pragma("unroll")                                                      \
      for (int s = 0; s < 4; ++s) {                                          \
        int i = ilo + ((s - ilo) & 3);                                       \
        if (i <= ihi) {                                                      \
          float w = dww[i][r - 2 * i + 3];                                   \
          accA[s] += w * z0;                                                 \
          accB[s] += w * z1;                                                 \
          bool done = (r == 2 * i + 4) ||                                    \
                      (r == UPN - 1 && 2 * i + 4 > UPN - 1);                 \
          if (done) {                                                        \
            float* dst = obase + ((size_t)i * IN_W + j0) * NCH + c0 + 2 * e; \
            *(f2*)dst         = accA[s];                                     \
            *(f2*)(dst + NCH) = accB[s];                                     \
            accA[s] = (f2){0.f, 0.f};                                        \
            accB[s] = (f2){0.f, 0.f};                                        \
          }                                                                  \
        }                                                                    \
      }                                                                      \
    }                                                                        \
  } while (0)

#define STEP(PH)                                                             \
  do {                                                                       \
    int m = mlo + mb + (PH);                                                 \
    if (m <= mhi) {                                                          \
      int ml = m - mlo;                                                      \
      f2 raw[8];                                                             \
      _Pragma("unroll")                                                      \
      for (int k = 0; k < 8; ++k)                                            \
        raw[k] = *(const f2*)&xin[ml][2 * cp + k][2 * e];                    \
      _Pragma("unroll")                                                      \
      for (int c = 0; c < 10; ++c) {                                         \
        tw[(PH) & 3][c] = wvv[c].x * raw[(c >> 1) + 0]                       \
                        + wvv[c].y * raw[(c >> 1) + 1]                       \
                        + wvv[c].z * raw[(c >> 1) + 2]                       \
                        + wvv[c].w * raw[(c >> 1) + 3];                      \
      }                                                                      \
      DO_R(2 * m - 3, ((PH) + 1) & 3, ((PH) + 2) & 3, ((PH) + 3) & 3, (PH) & 3); \
      DO_R(2 * m - 2, ((PH) + 1) & 3, ((PH) + 2) & 3, ((PH) + 3) & 3, (PH) & 3); \
    }                                                                        \
  } while (0)

  // 14 m-steps, unrolled in groups of 4 so ring slots are compile-time.
  for (int mb = 0; mb < 16; mb += 4) {
    STEP(0);
    STEP(1);
    STEP(2);
    STEP(3);
  }

#undef STEP
#undef DO_R
}

extern "C" void kernel_launch(void* const* d_in, const int* in_sizes, int n_in,
                              void* d_out, int out_size, void* d_ws, size_t ws_size,
                              hipStream_t stream) {
  const float* x = (const float*)d_in[0];
  float* out = (float*)d_out;
  actfilter_kernel<<<dim3(2048), dim3(256), 0, stream>>>(x, out);
}